// Round 7
// baseline (541.943 us; speedup 1.0000x reference)
//
#include <hip/hip_runtime.h>

#define DIM   64
#define KCB   1024
#define RPB   128          // rows per block

// ws layout (floats): ws[0] = loss accumulator; ws[256..1279] = csq[k]

__global__ void vq_prep(const float* __restrict__ cb, float* __restrict__ ws) {
    int k = blockIdx.x * blockDim.x + threadIdx.x;
    if (k < KCB) {
        const float* e = cb + (k << 6);
        {
            #pragma clang fp contract(off)
            float racc[8];
            #pragma unroll
            for (int j = 0; j < 8; ++j) racc[j] = e[j] * e[j];
            #pragma unroll
            for (int t = 1; t < 8; ++t) {
                #pragma unroll
                for (int j = 0; j < 8; ++j) racc[j] += e[8 * t + j] * e[8 * t + j];
            }
            ws[256 + k] = ((racc[0] + racc[1]) + (racc[2] + racc[3]))
                        + ((racc[4] + racc[5]) + (racc[6] + racc[7]));
        }
    }
    if (k == 0) ws[0] = 0.0f;
}

// 2D register-tiled VQ kernel. R6->R7 change: e-loads moved from the scalar
// pipe (s_load, OOO returns -> lgkmcnt(0) full drains + K$ thrash across 4
// quarters/CU was the shared-resource wall at ~244us) to the VECTOR pipe:
// per-lane global_load_dwordx4 of a wave-uniform address (TA coalesces to one
// L1 line + broadcast; in-order returns -> fine-grained vmcnt(N) pipelining;
// e lands in VGPRs directly consumable by v_fmac). A laundered "+v" zero
// offset stops the compiler re-scalarizing the uniform address.
//  - 128 rows/block, 36.5 KB LDS; wave q scans entry quarter [q*256,+256).
//  - lane tile: 2 rows x 16 entries (32 acc); per jb step: 2 ds_read_b128 +
//    16 global_load_dwordx4 + 128 fmas.
//  - numerics: per-dot j-chain strictly sequential, d=(A-2m)+cs, argmin
//    ascending strict-<, quarters combined ascending (bit-identical to R5/R6).
__global__ __launch_bounds__(256, 4) void vq_main(
        const float* __restrict__ in,
        const float* __restrict__ cb,
        const float* __restrict__ csq,      // = ws + 256
        float* __restrict__ codes_f,
        float* __restrict__ out,
        float* __restrict__ loss_acc)       // = ws + 0
{
    __shared__ float xs[RPB * DIM];         // 8192 words, swizzled x (32 KB)
    __shared__ float dtab[RPB * 4];         // per-row per-quarter best d (2 KB)
    __shared__ int   ktab[RPB * 4];         // per-row per-quarter best k (2 KB)
    __shared__ int   codes[RPB];            // 0.5 KB

    const int tid  = threadIdx.x;
    const int lane = tid & 63;
    const int q    = __builtin_amdgcn_readfirstlane(tid >> 6);   // entry quarter
    const size_t rowBase = (size_t)blockIdx.x * RPB;

    // ---- stage x, swizzled: word = row*64 + ((cj ^ (row&15))<<2) ----
    {
        const float4* gx = (const float4*)(in + rowBase * DIM);
        #pragma unroll
        for (int i = 0; i < 8; ++i) {
            int idx = i * 256 + tid;
            int row = idx >> 4, cj = idx & 15;
            float4 v = gx[idx];
            *(float4*)(xs + row * 64 + ((cj ^ (row & 15)) << 2)) = v;
        }
    }
    __syncthreads();

    // ---- A = ||x||^2 for my 2 rows (exact numpy pairwise-8 order) ----
    float A[2];
    #pragma unroll
    for (int ri = 0; ri < 2; ++ri) {
        const int row = lane + (ri << 6);       // (row&15) == (lane&15)
        float xv[64];
        #pragma unroll
        for (int cj = 0; cj < 16; ++cj) {
            float4 v = *(const float4*)(xs + row * 64 + ((cj ^ (lane & 15)) << 2));
            xv[cj*4+0]=v.x; xv[cj*4+1]=v.y; xv[cj*4+2]=v.z; xv[cj*4+3]=v.w;
        }
        {
            #pragma clang fp contract(off)
            float racc[8];
            #pragma unroll
            for (int j = 0; j < 8; ++j) racc[j] = xv[j] * xv[j];
            #pragma unroll
            for (int t = 1; t < 8; ++t) {
                #pragma unroll
                for (int j = 0; j < 8; ++j) racc[j] += xv[8*t+j] * xv[8*t+j];
            }
            A[ri] = ((racc[0] + racc[1]) + (racc[2] + racc[3]))
                  + ((racc[4] + racc[5]) + (racc[6] + racc[7]));
        }
    }

    // ---- main scan: my quarter's 256 entries, 16 at a time ----
    // Laundered zero offset -> compiler must treat the codebook address as
    // divergent -> vector loads (global_load_dwordx4), not s_load.
    int voff = 0;
    asm volatile("" : "+v"(voff));
    const float* cbv   = cb + ((size_t)q << 14) + voff;
    const float* csq_q = csq + (q << 8);

    float dmin[2] = {3.402823466e38f, 3.402823466e38f};
    int   kmin[2] = {0, 0};
    const int xb = lane * 64;

    #pragma unroll 1
    for (int ke = 0; ke < 256; ke += 16) {
        float m[2][16];
        #pragma unroll
        for (int ri = 0; ri < 2; ++ri)
            #pragma unroll
            for (int e = 0; e < 16; ++e) m[ri][e] = 0.0f;

        #pragma unroll 1
        for (int jb = 0; jb < 64; jb += 4) {
            const int slot4 = ((jb >> 2) ^ (lane & 15)) << 2;
            float4 a0 = *(const float4*)(xs + xb +        slot4);
            float4 a1 = *(const float4*)(xs + xb + 4096 + slot4);   // row lane+64
            #pragma unroll
            for (int e = 0; e < 16; ++e) {
                float4 ev = *(const float4*)(cbv + ((ke + e) << 6) + jb); // vector ld
                m[0][e] = __builtin_fmaf(a0.x, ev.x, m[0][e]);
                m[0][e] = __builtin_fmaf(a0.y, ev.y, m[0][e]);
                m[0][e] = __builtin_fmaf(a0.z, ev.z, m[0][e]);
                m[0][e] = __builtin_fmaf(a0.w, ev.w, m[0][e]);
                m[1][e] = __builtin_fmaf(a1.x, ev.x, m[1][e]);
                m[1][e] = __builtin_fmaf(a1.y, ev.y, m[1][e]);
                m[1][e] = __builtin_fmaf(a1.z, ev.z, m[1][e]);
                m[1][e] = __builtin_fmaf(a1.w, ev.w, m[1][e]);
            }
        }

        #pragma unroll
        for (int e = 0; e < 16; ++e) {
            float cse = csq_q[ke + e];              // uniform, tiny
            int gk = (q << 8) + ke + e;
            #pragma unroll
            for (int ri = 0; ri < 2; ++ri) {
                float d;
                {
                    #pragma clang fp contract(off)
                    d = (A[ri] - 2.0f * m[ri][e]) + cse;
                }
                if (d < dmin[ri]) { dmin[ri] = d; kmin[ri] = gk; }  // ascending, strict <
            }
        }
    }

    // ---- cross-quarter lex-min combine ----
    #pragma unroll
    for (int ri = 0; ri < 2; ++ri) {
        int row = lane + (ri << 6);
        dtab[row * 4 + q] = dmin[ri];
        ktab[row * 4 + q] = kmin[ri];
    }
    __syncthreads();

    float db = 0.0f;
    if (tid < RPB) {
        float dbest = dtab[tid * 4];
        int   kbest = ktab[tid * 4];
        #pragma unroll
        for (int qq = 1; qq < 4; ++qq) {    // ascending quarters, strict <
            float dq = dtab[tid * 4 + qq];
            int   kq = ktab[tid * 4 + qq];
            if (dq < dbest) { dbest = dq; kbest = kq; }
        }
        codes[tid] = kbest;
        codes_f[rowBase + tid] = (float)kbest;
        db = dbest;
    }
    __syncthreads();

    // ---- fused straight-through write: st = x + (q - x) ----
    {
        float4* gout = (float4*)(out + rowBase * DIM);
        #pragma unroll
        for (int i = 0; i < 8; ++i) {
            int idx = i * 256 + tid;
            int row = idx >> 4, cj = idx & 15;
            int code = codes[row];
            float4 qv = *(const float4*)(cb + ((size_t)code << 6) + (cj << 2));
            float4 xv = *(const float4*)(xs + row * 64 + ((cj ^ (row & 15)) << 2));
            float4 st;
            {
                #pragma clang fp contract(off)
                st.x = xv.x + (qv.x - xv.x);
                st.y = xv.y + (qv.y - xv.y);
                st.z = xv.z + (qv.z - xv.z);
                st.w = xv.w + (qv.w - xv.w);
            }
            gout[idx] = st;
        }
    }

    // ---- loss partial (dtab reused as reduction tree; tid>=128 contribute 0) ----
    __syncthreads();
    dtab[tid] = db;
    __syncthreads();
    #pragma unroll
    for (int s = 128; s > 0; s >>= 1) {
        if (tid < s) dtab[tid] += dtab[tid + s];
        __syncthreads();
    }
    if (tid == 0) atomicAdd(loss_acc, dtab[0]);
}

__global__ void vq_final(const float* __restrict__ ws, float* __restrict__ loss_out) {
    // loss = codebook_loss + BETA*commitment = 1.25 * mean((x-q)^2)
    loss_out[0] = 1.25f * ws[0] / 8388608.0f;
}

extern "C" void kernel_launch(void* const* d_in, const int* in_sizes, int n_in,
                              void* d_out, int out_size, void* d_ws, size_t ws_size,
                              hipStream_t stream) {
    const float* in = (const float*)d_in[0];   // (32,4096,64) fp32
    const float* cb = (const float*)d_in[1];   // (1024,64)    fp32
    float* out     = (float*)d_out;
    float* codes_f = out + 8388608;
    float* loss_p  = out + 8519680;
    float* ws      = (float*)d_ws;

    vq_prep <<<4,    256, 0, stream>>>(cb, ws);
    vq_main <<<1024, 256, 0, stream>>>(in, cb, ws + 256, codes_f, out, ws);
    vq_final<<<1,    1,   0, stream>>>(ws, loss_p);
}

// Round 9
// 319.313 us; speedup vs baseline: 1.6972x; 1.6972x over previous
//
#include <hip/hip_runtime.h>

typedef __attribute__((ext_vector_type(8))) short bf16x8;
typedef __attribute__((ext_vector_type(4))) float f32x4;
typedef unsigned int       uint32;
typedef unsigned long long uint64;

#define DIM    64
#define KCB    1024
#define RPB    128        // rows per block
#define CHUNK  128        // entries staged per LDS chunk
#define NCHUNK 8
#define QCAP   1536

// dynamic LDS layout (bytes)
#define OFF_XS    0        // 128*64 f32      = 32768
#define OFF_EHI   32768    // 128*64 bf16     = 16384
#define OFF_ELO   49152    // 16384
#define OFF_CSQ   65536    // 1024 f32        = 4096
#define OFF_A     69632    // 128 f32         = 512
#define OFF_DMIN  70144    // 128 f32         = 512
#define OFF_SLOT  70656    // 128 u64         = 1024
#define OFF_QUEUE 71680    // 1536 u32        = 6144
#define OFF_QCNT  77824    // 16
#define OFF_CODES 77840    // 128 i32         = 512
#define OFF_RED   78352    // 256 f32         = 1024
#define SMEM_BYTES 79376

__device__ __forceinline__ unsigned short f2bf(float f) {
    uint32 u = __float_as_uint(f);
    return (unsigned short)((u + 0x7fffu + ((u >> 16) & 1u)) >> 16);
}
__device__ __forceinline__ float bf2f(unsigned short h) {
    return __uint_as_float(((uint32)h) << 16);
}

// csq[k] = np.sum(cb*cb, axis=1) with numpy pairwise-8 order; zero loss acc.
__global__ void vq_prep(const float* __restrict__ cb, float* __restrict__ ws) {
    int k = blockIdx.x * blockDim.x + threadIdx.x;
    if (k < KCB) {
        const float* e = cb + (k << 6);
        {
            #pragma clang fp contract(off)
            float racc[8];
            #pragma unroll
            for (int j = 0; j < 8; ++j) racc[j] = e[j] * e[j];
            #pragma unroll
            for (int t = 1; t < 8; ++t) {
                #pragma unroll
                for (int j = 0; j < 8; ++j) racc[j] += e[8 * t + j] * e[8 * t + j];
            }
            ws[256 + k] = ((racc[0] + racc[1]) + (racc[2] + racc[3]))
                        + ((racc[4] + racc[5]) + (racc[6] + racc[7]));
        }
    }
    if (k == 0) ws[0] = 0.0f;
}

// Exact fp32 distance (bit-identical to the R1..R6 passing recipe) + lex-min
// update via packed u64 atomicMin: (d_bits<<32)|k. d>=0 so fp bits are
// order-monotone; equal d -> smaller k wins == numpy first-index tie-break.
__device__ __forceinline__ void exact_update(int row_l, int kg,
                                             const float* __restrict__ cb,
                                             const float* xs, const float* A_l,
                                             const float* csq_l, uint64* slot) {
    const float* ep = cb + ((size_t)kg << 6);
    const float* xr = xs + row_l * DIM;
    float m = 0.0f;
    #pragma unroll
    for (int c = 0; c < 16; ++c) {                 // j ascending, sequential chain
        float4 e4 = ((const float4*)ep)[c];
        float4 x4 = ((const float4*)xr)[c];
        m = __builtin_fmaf(x4.x, e4.x, m);
        m = __builtin_fmaf(x4.y, e4.y, m);
        m = __builtin_fmaf(x4.z, e4.z, m);
        m = __builtin_fmaf(x4.w, e4.w, m);
    }
    float d;
    {
        #pragma clang fp contract(off)
        d = (A_l[row_l] - 2.0f * m) + csq_l[kg];   // 2*m exact; 2 roundings, as ref
    }
    uint64 v = (((uint64)__float_as_uint(d)) << 32) | (uint32)kg;
    atomicMin(slot + row_l, v);
}

__global__ __launch_bounds__(256, 2) void vq_main(
        const float* __restrict__ in,
        const float* __restrict__ cb,
        const float* __restrict__ csq_g,    // = ws + 256
        float* __restrict__ codes_f,
        float* __restrict__ out,
        float* __restrict__ loss_acc)       // = ws + 0
{
    extern __shared__ char smem[];
    float*  xs     = (float*) (smem + OFF_XS);
    char*   ehi    = smem + OFF_EHI;
    char*   elo    = smem + OFF_ELO;
    float*  csq_l  = (float*) (smem + OFF_CSQ);
    float*  A_l    = (float*) (smem + OFF_A);
    float*  dmin_l = (float*) (smem + OFF_DMIN);
    uint64* slot   = (uint64*)(smem + OFF_SLOT);
    uint32* queue  = (uint32*)(smem + OFF_QUEUE);
    int*    qcnt   = (int*)   (smem + OFF_QCNT);
    int*    codes  = (int*)   (smem + OFF_CODES);
    float*  red    = (float*) (smem + OFF_RED);

    const int tid  = threadIdx.x;
    const int lane = tid & 63;
    const int w    = __builtin_amdgcn_readfirstlane(tid >> 6);
    const int q    = lane >> 4;             // quad 0..3 (per-lane)
    const int col  = lane & 15;
    const size_t rowBase = (size_t)blockIdx.x * RPB;

    // ---- stage x (row-major fp32) + init slot/qcnt ----
    {
        const uint4* gx = (const uint4*)(in + rowBase * DIM);
        uint4* lx = (uint4*)xs;
        #pragma unroll
        for (int i = 0; i < 8; ++i) lx[i * 256 + tid] = gx[i * 256 + tid];
    }
    if (tid < RPB) slot[tid] = ~0ull;
    if (tid == 0) *qcnt = 0;
    __syncthreads();

    // ---- A[row] exact (numpy pairwise-8) + stage csq ----
    if (tid < RPB) {
        const float* xr = xs + tid * DIM;
        {
            #pragma clang fp contract(off)
            float racc[8];
            #pragma unroll
            for (int j = 0; j < 8; ++j) racc[j] = xr[j] * xr[j];
            #pragma unroll
            for (int t = 1; t < 8; ++t) {
                #pragma unroll
                for (int j = 0; j < 8; ++j) racc[j] += xr[8*t+j] * xr[8*t+j];
            }
            A_l[tid] = ((racc[0] + racc[1]) + (racc[2] + racc[3]))
                     + ((racc[4] + racc[5]) + (racc[6] + racc[7]));
        }
    }
    #pragma unroll
    for (int i = 0; i < 4; ++i) csq_l[i * 256 + tid] = csq_g[i * 256 + tid];
    __syncthreads();

    // ---- A-frags (bf16 hi/lo splits) into registers, once ----
    // A-layout: lane holds A[m=col][k=q*8+j]; frag (rt,kh): dims 32*kh+q*8..+7
    bf16x8 xhi[2][2], xlo[2][2];
    float  A_reg[2][4];
    #pragma unroll
    for (int rt = 0; rt < 2; ++rt) {
        const int row_l = (w * 2 + rt) * 16 + col;
        const float* xp = xs + row_l * DIM;
        #pragma unroll
        for (int kh = 0; kh < 2; ++kh) {
            const int base = kh * 32 + q * 8;
            #pragma unroll
            for (int j = 0; j < 8; ++j) {
                float f = xp[base + j];
                unsigned short hs = f2bf(f);
                xhi[rt][kh][j] = (short)hs;
                xlo[rt][kh][j] = (short)f2bf(f - bf2f(hs));
            }
        }
        #pragma unroll
        for (int r = 0; r < 4; ++r)
            A_reg[rt][r] = A_l[(w * 2 + rt) * 16 + q * 4 + r];
    }

    float dm[2][4];
    #pragma unroll
    for (int rt = 0; rt < 2; ++rt)
        #pragma unroll
        for (int r = 0; r < 4; ++r) dm[rt][r] = 3.402823466e38f;

    // ================= two passes over entry chunks =================
    for (int pass = 0; pass < 2; ++pass) {
        float thr[2][4];
        if (pass == 1) {
            // margin >= 2*B; B ~ A*2.4e-7 + 1.5e-6 (final-add rounding dominates)
            #pragma unroll
            for (int rt = 0; rt < 2; ++rt)
                #pragma unroll
                for (int r = 0; r < 4; ++r)
                    thr[rt][r] = dmin_l[(w*2+rt)*16 + q*4 + r]
                               + __builtin_fmaf(A_reg[rt][r], 1e-6f, 4e-5f);
        }

        for (int c = 0; c < NCHUNK; ++c) {
            __syncthreads();
            // ---- stage e-chunk as bf16 hi/lo, swizzled 16B chunks ----
            {
                const int entry_l = tid >> 1, half = tid & 1;
                const float* ep = cb + ((size_t)(c * CHUNK + entry_l)) * DIM + half * 32;
                #pragma unroll
                for (int c2 = 0; c2 < 4; ++c2) {
                    unsigned short hs[8], ls[8];
                    #pragma unroll
                    for (int j = 0; j < 8; ++j) {
                        float f = ep[c2 * 8 + j];
                        hs[j] = f2bf(f);
                        ls[j] = f2bf(f - bf2f(hs[j]));
                    }
                    const int swz = (half * 4 + c2) ^ (entry_l & 7);
                    uint4 hv, lv;
                    hv.x = (uint32)hs[0] | ((uint32)hs[1] << 16);
                    hv.y = (uint32)hs[2] | ((uint32)hs[3] << 16);
                    hv.z = (uint32)hs[4] | ((uint32)hs[5] << 16);
                    hv.w = (uint32)hs[6] | ((uint32)hs[7] << 16);
                    lv.x = (uint32)ls[0] | ((uint32)ls[1] << 16);
                    lv.y = (uint32)ls[2] | ((uint32)ls[3] << 16);
                    lv.z = (uint32)ls[4] | ((uint32)ls[5] << 16);
                    lv.w = (uint32)ls[6] | ((uint32)ls[7] << 16);
                    *(uint4*)(ehi + entry_l * 128 + swz * 16) = hv;
                    *(uint4*)(elo + entry_l * 128 + swz * 16) = lv;
                }
            }
            __syncthreads();

            // ---- 8 entry-tiles of 16 ----
            for (int et = 0; et < 8; ++et) {
                const int entry_l = et * 16 + col;
                const int kg      = c * CHUNK + entry_l;
                const float cse   = csq_l[kg];
                const int swz0 = (0 * 4 + q) ^ (lane & 7);
                const int swz1 = (1 * 4 + q) ^ (lane & 7);
                bf16x8 bh0 = *(const bf16x8*)(ehi + entry_l * 128 + swz0 * 16);
                bf16x8 bh1 = *(const bf16x8*)(ehi + entry_l * 128 + swz1 * 16);
                bf16x8 bl0 = *(const bf16x8*)(elo + entry_l * 128 + swz0 * 16);
                bf16x8 bl1 = *(const bf16x8*)(elo + entry_l * 128 + swz1 * 16);

                #pragma unroll
                for (int rt = 0; rt < 2; ++rt) {
                    f32x4 acc = {0.f, 0.f, 0.f, 0.f};
                    acc = __builtin_amdgcn_mfma_f32_16x16x32_bf16(xhi[rt][0], bh0, acc, 0, 0, 0);
                    acc = __builtin_amdgcn_mfma_f32_16x16x32_bf16(xlo[rt][0], bh0, acc, 0, 0, 0);
                    acc = __builtin_amdgcn_mfma_f32_16x16x32_bf16(xhi[rt][0], bl0, acc, 0, 0, 0);
                    acc = __builtin_amdgcn_mfma_f32_16x16x32_bf16(xhi[rt][1], bh1, acc, 0, 0, 0);
                    acc = __builtin_amdgcn_mfma_f32_16x16x32_bf16(xlo[rt][1], bh1, acc, 0, 0, 0);
                    acc = __builtin_amdgcn_mfma_f32_16x16x32_bf16(xhi[rt][1], bl1, acc, 0, 0, 0);
                    #pragma unroll
                    for (int r = 0; r < 4; ++r) {
                        float dh = __builtin_fmaf(-2.0f, acc[r], A_reg[rt][r]) + cse;
                        if (pass == 0) {
                            dm[rt][r] = fminf(dm[rt][r], dh);
                        } else if (dh <= thr[rt][r]) {
                            const int row_l = (w*2+rt)*16 + q*4 + r;
                            int idx = atomicAdd(qcnt, 1);
                            if (idx < QCAP) queue[idx] = ((uint32)row_l << 16) | (uint32)kg;
                            else exact_update(row_l, kg, cb, xs, A_l, csq_l, slot);
                        }
                    }
                }
            }
        }

        if (pass == 0) {
            // cross-lane min over the 16 cols of each quad (intra-wave)
            #pragma unroll
            for (int rt = 0; rt < 2; ++rt)
                #pragma unroll
                for (int r = 0; r < 4; ++r) {
                    float v = dm[rt][r];
                    v = fminf(v, __shfl_xor(v, 1));
                    v = fminf(v, __shfl_xor(v, 2));
                    v = fminf(v, __shfl_xor(v, 4));
                    v = fminf(v, __shfl_xor(v, 8));
                    if (col == 0) dmin_l[(w*2+rt)*16 + q*4 + r] = v;
                }
            __syncthreads();
        }
    }

    // ---- drain hit queue: one exact fp32 chain per hit, spread over lanes ----
    __syncthreads();
    {
        int nq = *qcnt;
        if (nq > QCAP) nq = QCAP;
        for (int i = tid; i < nq; i += 256) {
            uint32 pk = queue[i];
            exact_update((int)(pk >> 16), (int)(pk & 0xffffu), cb, xs, A_l, csq_l, slot);
        }
    }
    __syncthreads();

    // ---- per-row result ----
    float db = 0.0f;
    if (tid < RPB) {
        uint64 s = slot[tid];
        int kbest = (int)(s & 0xffffffffu);
        db = __uint_as_float((uint32)(s >> 32));
        codes[tid] = kbest;
        codes_f[rowBase + tid] = (float)kbest;
    }
    red[tid] = db;          // tid>=128 contribute 0
    __syncthreads();

    // ---- straight-through write ----
    {
        float4* gout = (float4*)(out + rowBase * DIM);
        const float4* lx = (const float4*)xs;
        #pragma unroll
        for (int i = 0; i < 8; ++i) {
            int idx = i * 256 + tid;
            int row = idx >> 4, cj = idx & 15;
            int code = codes[row];
            float4 qv = *(const float4*)(cb + ((size_t)code << 6) + (cj << 2));
            float4 xv = lx[idx];
            float4 st;
            {
                #pragma clang fp contract(off)
                st.x = xv.x + (qv.x - xv.x);
                st.y = xv.y + (qv.y - xv.y);
                st.z = xv.z + (qv.z - xv.z);
                st.w = xv.w + (qv.w - xv.w);
            }
            gout[idx] = st;
        }
    }

    // ---- loss partial ----
    #pragma unroll
    for (int s = 128; s > 0; s >>= 1) {
        if (tid < s) red[tid] += red[tid + s];
        __syncthreads();
    }
    if (tid == 0) atomicAdd(loss_acc, red[0]);
}

__global__ void vq_final(const float* __restrict__ ws, float* __restrict__ loss_out) {
    loss_out[0] = 1.25f * ws[0] / 8388608.0f;   // 1.25 * mean((x-q)^2)
}

extern "C" void kernel_launch(void* const* d_in, const int* in_sizes, int n_in,
                              void* d_out, int out_size, void* d_ws, size_t ws_size,
                              hipStream_t stream) {
    const float* in = (const float*)d_in[0];   // (32,4096,64) fp32
    const float* cb = (const float*)d_in[1];   // (1024,64)    fp32
    float* out     = (float*)d_out;
    float* codes_f = out + 8388608;
    float* loss_p  = out + 8519680;
    float* ws      = (float*)d_ws;

    (void)hipFuncSetAttribute((const void*)vq_main,
                              hipFuncAttributeMaxDynamicSharedMemorySize, SMEM_BYTES);

    vq_prep <<<4,    256, 0,          stream>>>(cb, ws);
    vq_main <<<1024, 256, SMEM_BYTES, stream>>>(in, cb, ws + 256, codes_f, out, ws);
    vq_final<<<1,    1,   0,          stream>>>(ws, loss_p);
}